// Round 1
// baseline (57.553 us; speedup 1.0000x reference)
//
#include <hip/hip_runtime.h>
#include <math.h>

#define NL 32
#define NLEAVES 8192

// ---- LDS layout (floats) ----
// E: exp(T) transposed, float4-packed over r: E4[(l*8+r4)*32+lp] = exp(T[lp][l][4*r4..+3])
constexpr int E_F32   = 32768;        // 128 KB
constexpr int ROWP    = 36;           // aexp row pad (16B-aligned rows: 144B)
constexpr int NROWS   = 32;           // max rows per buffer (IN <= 32)
constexpr int PARTP   = 33;           // partial-sum pad (conflict-free)
constexpr int OFF_E   = 0;
constexpr int OFF_A   = OFF_E + E_F32;            // bufA: 32*36
constexpr int OFF_B   = OFF_A + NROWS * ROWP;     // bufB: 32*36
constexpr int OFF_P0  = OFF_B + NROWS * ROWP;     // part0: 32*33
constexpr int OFF_P1  = OFF_P0 + 32 * PARTP;      // part1: 32*33
constexpr int OFF_RA  = OFF_P1 + 32 * PARTP;      // rmaxA: 32
constexpr int OFF_RB  = OFF_RA + NROWS;           // rmaxB: 32
constexpr int SMEM_F32 = OFF_RB + NROWS;
constexpr size_t SMEM_BYTES = (size_t)SMEM_F32 * 4;   // ~149 KB

// K0: transpose + exp trans[lp][l][r] -> wsE[(l*8+r4)*32+lp] (float4 units)
__global__ void k0_exp_transpose(const float* __restrict__ trans, float* __restrict__ wsE) {
    const int t = threadIdx.x;          // 0..255 => lr
    const int lp = blockIdx.x;          // 0..31
    const float4* src = (const float4*)trans;   // trans4[lp*256 + lr]
    float4* dst = (float4*)wsE;                 // ws4[lr*32 + lp]
    float4 v = src[lp * 256 + t];
    float4 e;
    e.x = expf(v.x); e.y = expf(v.y); e.z = expf(v.z); e.w = expf(v.w);
    dst[t * 32 + lp] = e;
}

// Generic subtree-reduction kernel.
// Block `blk` takes IN consecutive input rows (scores) starting at row blk*IN,
// reduces LEVELS = log2(IN) levels, writes its root row to out[blk*32 + lp].
// NTOT = global node count at the input level (for internal_emissions offsets).
__global__ __launch_bounds__(1024)
void tree_levels(const float* __restrict__ in, float* __restrict__ out,
                 const float* __restrict__ iem, const float* __restrict__ wsE,
                 int IN, int NTOT, int LEVELS) {
    extern __shared__ __align__(16) float sm[];
    float* E    = sm + OFF_E;
    float* bufA = sm + OFF_A;
    float* bufB = sm + OFF_B;
    float* p0   = sm + OFF_P0;
    float* p1   = sm + OFF_P1;
    float* rA   = sm + OFF_RA;
    float* rB   = sm + OFF_RB;

    const int tid = threadIdx.x;
    const int lp  = tid & 31;
    const int q   = tid >> 5;       // 0..31
    const int blk = blockIdx.x;

    // --- load exp(T) (transposed layout) into LDS: coalesced, conflict-free ---
    {
        const float4* src = (const float4*)wsE;
        float4* dst = (float4*)E;
        #pragma unroll
        for (int i = 0; i < 8; ++i) dst[tid + i * 1024] = src[tid + i * 1024];
    }
    // --- pre-pass: input rows -> aexp + rowmax ---
    if (tid < IN * 32) {
        const int row = q;
        float v = in[(blk * IN + row) * 32 + lp];
        float gm = v;
        #pragma unroll
        for (int k = 16; k >= 1; k >>= 1) gm = fmaxf(gm, __shfl_xor(gm, k));
        bufA[row * ROWP + lp] = expf(v - gm);
        if (lp == 0) rA[row] = gm;
    }
    __syncthreads();

    float* prev = bufA; float* rprev = rA;
    float* next = bufB; float* rnext = rB;

    for (int k = 1; k <= LEVELS; ++k) {
        const int m = IN >> k;                       // nodes this level (local)
        const int ntiles = (m >= 2) ? (m >> 1) : 1;  // 2 nodes per thread-slot
        const int G = 32 / ntiles;                   // l-split segments
        const int sh = 31 - __clz(ntiles);
        const int tile = q & (ntiles - 1);
        const int seg  = q >> sh;
        // children rows for node0 = 2*tile, node1 = 2*tile+1
        const int ra0 = 4 * tile, rb0 = 4 * tile + 1;
        const int ra1 = 4 * tile + 2, rb1 = 4 * tile + 3;   // garbage-but-safe when m==1

        // right-child rows in registers (broadcast b128 reads)
        float4 b0[8], b1[8];
        {
            const float4* pb0 = (const float4*)(prev + rb0 * ROWP);
            const float4* pb1 = (const float4*)(prev + rb1 * ROWP);
            #pragma unroll
            for (int r = 0; r < 8; ++r) { b0[r] = pb0[r]; b1[r] = pb1[r]; }
        }
        float s0 = 0.f, s1 = 0.f;
        for (int li = 0; li < ntiles; ++li) {        // llen == ntiles
            const int l = seg * ntiles + li;
            const float a0 = prev[ra0 * ROWP + l];
            const float a1 = prev[ra1 * ROWP + l];
            const float4* ec = (const float4*)E + l * 256 + lp;  // step 32 per r4
            float u0 = 0.f, u1 = 0.f;
            #pragma unroll
            for (int r4 = 0; r4 < 8; ++r4) {
                const float4 e = ec[r4 * 32];
                u0 = fmaf(b0[r4].x, e.x, u0); u0 = fmaf(b0[r4].y, e.y, u0);
                u0 = fmaf(b0[r4].z, e.z, u0); u0 = fmaf(b0[r4].w, e.w, u0);
                u1 = fmaf(b1[r4].x, e.x, u1); u1 = fmaf(b1[r4].y, e.y, u1);
                u1 = fmaf(b1[r4].z, e.z, u1); u1 = fmaf(b1[r4].w, e.w, u1);
            }
            s0 = fmaf(a0, u0, s0);
            s1 = fmaf(a1, u1, s1);
        }
        p0[q * PARTP + lp] = s0;
        p1[q * PARTP + lp] = s1;
        __syncthreads();

        if (tid < m * 32) {
            const int node = q;                 // < m
            const int par  = node & 1;
            const int tl   = node >> 1;
            const float* pp = par ? p1 : p0;
            float acc = 0.f;
            for (int s = 0; s < G; ++s) acc += pp[(s * ntiles + tl) * PARTP + lp];
            const float em = iem[((NLEAVES - 2 * (NTOT >> k)) + blk * m + node) * 32 + lp];
            const float raw = em + rprev[2 * node] + rprev[2 * node + 1] + logf(acc);
            if (k == LEVELS) {
                out[blk * 32 + lp] = raw;       // m==1, node==0
            } else {
                float gm = raw;
                #pragma unroll
                for (int kk = 16; kk >= 1; kk >>= 1) gm = fmaxf(gm, __shfl_xor(gm, kk));
                next[node * ROWP + lp] = expf(raw - gm);
                if (lp == 0) rnext[node] = gm;
            }
        }
        __syncthreads();
        float* t1 = prev; prev = next; next = t1;
        float* t2 = rprev; rprev = rnext; rnext = t2;
    }
}

extern "C" void kernel_launch(void* const* d_in, const int* in_sizes, int n_in,
                              void* d_out, int out_size, void* d_ws, size_t ws_size,
                              hipStream_t stream) {
    const float* leaf  = (const float*)d_in[0];   // [8192,32]
    const float* iem   = (const float*)d_in[1];   // [8191,32]
    const float* trans = (const float*)d_in[2];   // [32,32,32]
    float* out = (float*)d_out;                   // [32]

    float* wsE = (float*)d_ws;                    // 32768 f32 (128 KB)
    float* s1  = wsE + 32768;                     // 256*32 f32
    float* s2  = s1 + 256 * 32;                   // 8*32 f32

    (void)hipFuncSetAttribute((const void*)tree_levels,
                              hipFuncAttributeMaxDynamicSharedMemorySize,
                              (int)SMEM_BYTES);

    // K0: exp + transpose of trans into ws
    k0_exp_transpose<<<32, 256, 0, stream>>>(trans, wsE);
    // K1: 8192 leaves -> 256 roots (levels n=4096..256), full chip
    tree_levels<<<256, 1024, SMEM_BYTES, stream>>>(leaf, s1, iem, wsE, 32, 8192, 5);
    // K2: 256 -> 8 (levels n=128..8)
    tree_levels<<<8, 1024, SMEM_BYTES, stream>>>(s1, s2, iem, wsE, 32, 256, 5);
    // K3: 8 -> 1 (levels n=4,2,1)
    tree_levels<<<1, 1024, SMEM_BYTES, stream>>>(s2, out, iem, wsE, 8, 8, 3);
}